// Round 3
// baseline (633.925 us; speedup 1.0000x reference)
//
#include <hip/hip_runtime.h>

// DiceLoss2: B=16, C=21, H=W=512. Inputs: y_pred (f32), y_true (f32 one-hot), bg (int scalar).
// Output: single f32 scalar.
//
// R3: perfectly-balanced persistent grid. 2048 blocks (8/CU x 256 CU), each
// reduces a contiguous 1/2048 slice of the flat (b,c,h,w) index space:
// 10752 float4s per stream per block = exactly 42 iters/thread, zero tail,
// single scheduling round, one long contiguous sweep per stream per block.
// A slice crosses at most ONE (b,c)-plane boundary (10752 < 65536 f4/plane),
// so each block keeps two accumulator sets and writes two records
// (st, sp, stp, plane_id). Epilogue scatters 4096 records into per-plane
// bins via shared atomics, then computes the loss.
//
// NT loads kept (R1 A/B: cached loads +27 us — poison-fill dirty lines in
// L2/L3 make allocating reads pay writeback evictions; NT avoids that).
// Unroll depth ~7 (R2: 8 was neutral vs 4 -> not issue-limited; keep deep).

#define BB 16
#define CC 21
#define HW (512 * 512)
#define NPLANES (BB * CC)            // 336
#define HW_F4 (HW / 4)               // 65536 float4s per plane
#define TOTAL_F4 (NPLANES * HW_F4)   // 22,020,096
#define NBLK 2048
#define PER_BLK (TOTAL_F4 / NBLK)    // 10752 float4s per block
#define PER_THREAD (PER_BLK / 256)   // 42 iterations
#define NREC (NBLK * 2)              // 4096 records of 4 floats = 64 KiB ws

typedef float floatx4 __attribute__((ext_vector_type(4)));

__global__ __launch_bounds__(256) void dice_reduce_kernel(
    const float* __restrict__ y_pred,
    const float* __restrict__ y_true,
    float* __restrict__ part)   // [NREC][4]: st, sp, stp, plane
{
    const int blk = blockIdx.x;
    const int tid = threadIdx.x;

    const size_t f4base = (size_t)blk * PER_BLK;
    const floatx4* __restrict__ p4 = (const floatx4*)y_pred + f4base;
    const floatx4* __restrict__ t4 = (const floatx4*)y_true + f4base;

    const int p0 = (int)(f4base >> 16);                        // first plane (f4/plane = 2^16)
    const int p1 = (int)((f4base + PER_BLK - 1) >> 16);        // last plane (== p0 or p0+1)
    // local f4 index < bound  ->  plane p0
    const size_t rem = (((size_t)(p0 + 1)) << 16) - f4base;
    const int bound = rem < (size_t)PER_BLK ? (int)rem : PER_BLK;

    float st0 = 0.f, sp0 = 0.f, stp0 = 0.f;
    float st1 = 0.f, sp1 = 0.f, stp1 = 0.f;

    #pragma unroll 7
    for (int k = 0; k < PER_THREAD; ++k) {
        const int i = tid + k * 256;
        floatx4 p = __builtin_nontemporal_load(&p4[i]);
        floatx4 t = __builtin_nontemporal_load(&t4[i]);
        const float s_p  = (p.x + p.y) + (p.z + p.w);
        const float s_t  = (t.x + t.y) + (t.z + t.w);
        const float s_tp = (t.x * p.x + t.y * p.y) + (t.z * p.z + t.w * p.w);
        if (i < bound) { sp0 += s_p; st0 += s_t; stp0 += s_tp; }
        else           { sp1 += s_p; st1 += s_t; stp1 += s_tp; }
    }

    // wave64 shuffle reduction over all 6 partials
    #pragma unroll
    for (int off = 32; off > 0; off >>= 1) {
        st0  += __shfl_down(st0,  off, 64);
        sp0  += __shfl_down(sp0,  off, 64);
        stp0 += __shfl_down(stp0, off, 64);
        st1  += __shfl_down(st1,  off, 64);
        sp1  += __shfl_down(sp1,  off, 64);
        stp1 += __shfl_down(stp1, off, 64);
    }

    __shared__ float sm[6][4];
    const int wave = tid >> 6;
    const int lane = tid & 63;
    if (lane == 0) {
        sm[0][wave] = st0; sm[1][wave] = sp0; sm[2][wave] = stp0;
        sm[3][wave] = st1; sm[4][wave] = sp1; sm[5][wave] = stp1;
    }
    __syncthreads();

    if (tid == 0) {
        float r0 = (sm[0][0] + sm[0][1]) + (sm[0][2] + sm[0][3]);
        float r1 = (sm[1][0] + sm[1][1]) + (sm[1][2] + sm[1][3]);
        float r2 = (sm[2][0] + sm[2][1]) + (sm[2][2] + sm[2][3]);
        float r3 = (sm[3][0] + sm[3][1]) + (sm[3][2] + sm[3][3]);
        float r4 = (sm[4][0] + sm[4][1]) + (sm[4][2] + sm[4][3]);
        float r5 = (sm[5][0] + sm[5][1]) + (sm[5][2] + sm[5][3]);
        floatx4* rec = (floatx4*)part;
        floatx4 a; a.x = r0; a.y = r1; a.z = r2; a.w = (float)p0;
        floatx4 b; b.x = r3; b.y = r4; b.z = r5; b.w = (float)p1;
        rec[blk * 2 + 0] = a;   // if p1 == p0, record b is all-zero sums: harmless
        rec[blk * 2 + 1] = b;
    }
}

__global__ __launch_bounds__(512) void dice_final_kernel(
    const float* __restrict__ part,
    const int* __restrict__ bg_ptr,
    float* __restrict__ out)
{
    const float eps = 1e-11f;
    __shared__ float ta_s[NPLANES], tb_s[NPLANES], in_s[NPLANES];
    __shared__ float dice_sum[BB];
    __shared__ int   valid_cnt[BB];

    const int tid = threadIdx.x;
    for (int i = tid; i < NPLANES; i += 512) { ta_s[i] = 0.f; tb_s[i] = 0.f; in_s[i] = 0.f; }
    if (tid < BB) { dice_sum[tid] = 0.f; valid_cnt[tid] = 0; }
    __syncthreads();

    // 4096 records / 512 threads = 8 iterations, coalesced 16B reads
    for (int r = tid; r < NREC; r += 512) {
        floatx4 rec = *(const floatx4*)(part + (size_t)r * 4);
        const int pl = (int)rec.w;
        atomicAdd(&ta_s[pl], rec.x);
        atomicAdd(&tb_s[pl], rec.y);
        atomicAdd(&in_s[pl], rec.z);
    }
    __syncthreads();

    const int bg = *bg_ptr;
    if (tid < NPLANES) {
        const int c = tid % CC;
        const int b = tid / CC;
        if (c >= bg) {
            const float ta = ta_s[tid];
            if (ta != 0.0f) {   // exact: ta is an integer-valued fp32 count < 2^24
                const float dice = 2.0f * in_s[tid] / (ta + tb_s[tid] + eps);
                atomicAdd(&dice_sum[b], dice);
                atomicAdd(&valid_cnt[b], 1);
            }
        }
    }
    __syncthreads();

    if (tid == 0) {
        float sum_tmp = 0.0f;
        int cpt1 = 0;
        for (int b = 0; b < BB; b++) {
            const float denom = (float)valid_cnt[b] - (float)bg;
            if (denom != 0.0f) {
                sum_tmp += dice_sum[b] / denom;
                cpt1++;
            }
        }
        const float loss = 1.0f - sum_tmp / fmaxf((float)cpt1, 1.0f);
        out[0] = (cpt1 > 0) ? loss : -1.0f;
    }
}

extern "C" void kernel_launch(void* const* d_in, const int* in_sizes, int n_in,
                              void* d_out, int out_size, void* d_ws, size_t ws_size,
                              hipStream_t stream) {
    const float* y_pred = (const float*)d_in[0];
    const float* y_true = (const float*)d_in[1];
    const int*   bg_ptr = (const int*)d_in[2];
    float* out  = (float*)d_out;
    float* part = (float*)d_ws;   // NREC * 4 floats = 64 KiB, no init needed

    dice_reduce_kernel<<<NBLK, 256, 0, stream>>>(y_pred, y_true, part);
    dice_final_kernel<<<1, 512, 0, stream>>>(part, bg_ptr, out);
}

// Round 5
// 617.183 us; speedup vs baseline: 1.0271x; 1.0271x over previous
//
#include <hip/hip_runtime.h>

// DiceLoss2: B=16, C=21, H=W=512. Inputs: y_pred (f32), y_true (f32 one-hot), bg (int scalar).
// Output: single f32 scalar.
//
// Structure (R0/R2-proven): (1) atomic-free split reduction — each block
// reduces a contiguous chunk of one (b,c) plane, writes 3 private partials;
// (2) one-block epilogue reduces partials and computes the loss.
//
// R5 = R4 resubmitted (R4 bench was an infra failure, no measurement).
// Change vs R2: 512-thread blocks, __launch_bounds__(512,8) (VGPR<=64 -> 4
// blocks/CU = 32 waves/CU, same occupancy as before) with SPLIT=8. This
// HALVES the number of independent read streams per CU (8 vs 16): testing
// whether DRAM row-buffer thrash from ~4096 concurrent streams is what pins
// the NT dual-stream read rate at ~3.9 TB/s (vs 6.55 TB/s the fills write).
//
// Kept: NT loads (R1 A/B: cached +27 us — dirty poison-fill lines in L2/L3
// make allocating reads pay eviction writebacks). Unroll 4 (R2: 8 neutral;
// 4 keeps the body within the 64-VGPR budget, no spill).
// Reverted: R3 persistent slicing (+20 us regression).

#define BB 16
#define CC 21
#define HW (512 * 512)
#define SPLIT 8
#define CHUNK (HW / SPLIT)      // 32768 elements per block
#define NBC (BB * CC)           // 336
#define NPART (NBC * SPLIT)     // 2688 partial slots per quantity
#define NTHR 512

// Native clang vector type: __builtin_nontemporal_load requires a pointer to
// int/float/pointer or a VECTOR of such — HIP's float4 is a struct and fails.
typedef float floatx4 __attribute__((ext_vector_type(4)));

__global__ __launch_bounds__(NTHR, 8) void dice_reduce_kernel(
    const float* __restrict__ y_pred,
    const float* __restrict__ y_true,
    const int* __restrict__ bg_ptr,
    float* __restrict__ part)   // [3][NPART]: st, sp, stp
{
    const int blk   = blockIdx.x;
    const int split = blk % SPLIT;
    const int bc    = blk / SPLIT;     // 0..NBC-1
    const int c     = bc % CC;
    const int bg    = *bg_ptr;
    if (c < bg) return;                // sliced-away channel: final kernel skips its slots

    const size_t base = (size_t)bc * HW + (size_t)split * CHUNK;
    const floatx4* __restrict__ p4 = (const floatx4*)(y_pred + base);
    const floatx4* __restrict__ t4 = (const floatx4*)(y_true + base);

    float st = 0.0f, sp = 0.0f, stp = 0.0f;
    const int tid = threadIdx.x;

    // CHUNK/4 = 8192 float4s, 512 threads -> 16 compile-time iterations,
    // coalesced 16B/lane. unroll 4 => 8 loads (8 KB/wave) in flight, ~56 VGPR.
    #pragma unroll 4
    for (int k = 0; k < (CHUNK / 4) / NTHR; ++k) {
        const int i = tid + k * NTHR;
        floatx4 p = __builtin_nontemporal_load(&p4[i]);
        floatx4 t = __builtin_nontemporal_load(&t4[i]);
        sp  += (p.x + p.y) + (p.z + p.w);
        st  += (t.x + t.y) + (t.z + t.w);
        stp += (t.x * p.x + t.y * p.y) + (t.z * p.z + t.w * p.w);
    }

    // wave64 shuffle reduction
    #pragma unroll
    for (int off = 32; off > 0; off >>= 1) {
        st  += __shfl_down(st,  off, 64);
        sp  += __shfl_down(sp,  off, 64);
        stp += __shfl_down(stp, off, 64);
    }

    __shared__ float sm[3][8];
    const int wave = tid >> 6;
    const int lane = tid & 63;
    if (lane == 0) { sm[0][wave] = st; sm[1][wave] = sp; sm[2][wave] = stp; }
    __syncthreads();

    if (tid == 0) {
        float r0 = 0.f, r1 = 0.f, r2 = 0.f;
        #pragma unroll
        for (int w = 0; w < NTHR / 64; ++w) {
            r0 += sm[0][w]; r1 += sm[1][w]; r2 += sm[2][w];
        }
        part[0 * NPART + blk] = r0;
        part[1 * NPART + blk] = r1;
        part[2 * NPART + blk] = r2;
    }
}

__global__ __launch_bounds__(384) void dice_final_kernel(
    const float* __restrict__ part,
    const int* __restrict__ bg_ptr,
    float* __restrict__ out)
{
    const float eps = 1e-11f;
    const int bg = *bg_ptr;
    __shared__ float dice_sum[BB];
    __shared__ int   valid_cnt[BB];

    const int tid = threadIdx.x;
    if (tid < BB) { dice_sum[tid] = 0.0f; valid_cnt[tid] = 0; }
    __syncthreads();

    if (tid < NBC) {
        const int c = tid % CC;
        const int b = tid / CC;
        if (c >= bg) {
            float ta = 0.0f, tb = 0.0f, inter = 0.0f;
            #pragma unroll
            for (int s = 0; s < SPLIT; s++) {
                ta    += part[0 * NPART + tid * SPLIT + s];
                tb    += part[1 * NPART + tid * SPLIT + s];
                inter += part[2 * NPART + tid * SPLIT + s];
            }
            if (ta != 0.0f) {   // exact: ta is an integer-valued fp32 count < 2^24
                float dice = 2.0f * inter / (ta + tb + eps);
                atomicAdd(&dice_sum[b], dice);
                atomicAdd(&valid_cnt[b], 1);
            }
        }
    }
    __syncthreads();

    if (tid == 0) {
        float sum_tmp = 0.0f;
        int cpt1 = 0;
        for (int b = 0; b < BB; b++) {
            float denom = (float)valid_cnt[b] - (float)bg;
            if (denom != 0.0f) {
                sum_tmp += dice_sum[b] / denom;
                cpt1++;
            }
        }
        float loss = 1.0f - sum_tmp / fmaxf((float)cpt1, 1.0f);
        out[0] = (cpt1 > 0) ? loss : -1.0f;
    }
}

extern "C" void kernel_launch(void* const* d_in, const int* in_sizes, int n_in,
                              void* d_out, int out_size, void* d_ws, size_t ws_size,
                              hipStream_t stream) {
    const float* y_pred = (const float*)d_in[0];
    const float* y_true = (const float*)d_in[1];
    const int*   bg_ptr = (const int*)d_in[2];
    float* out  = (float*)d_out;
    float* part = (float*)d_ws;   // 3 * NPART floats = 32.25 KB, no init needed

    dice_reduce_kernel<<<NBC * SPLIT, NTHR, 0, stream>>>(y_pred, y_true, bg_ptr, part);
    dice_final_kernel<<<1, 384, 0, stream>>>(part, bg_ptr, out);
}